// Round 3
// baseline (1371.835 us; speedup 1.0000x reference)
//
#include <hip/hip_runtime.h>

// GraphConv: out[t] += input[s] * (esgn*enorm)  over 3.2M edges, D=32 fp32.
// Round 3: FIX — harness passes integer inputs as int32 (NOT int64 as the
// reference declares). Prior rounds read eidx as long long* -> OOB tidx reads
// and wild atomic stores -> GPU page fault -> harness process death.
// Design: 8 lanes/edge, float4 gather, scalar fp32 atomics scatter.

__global__ __launch_bounds__(256) void graphconv_scatter(
    const float* __restrict__ input,
    const int* __restrict__ sidx,
    const int* __restrict__ tidx,
    const float* __restrict__ enorm,
    const float* __restrict__ esgn,
    float* __restrict__ out,
    int n_edges)
{
    int t = blockIdx.x * blockDim.x + threadIdx.x;
    int e = t >> 3;          // 8 threads per edge
    int sub = t & 7;         // which float4 of the 32-float row
    if (e >= n_edges) return;

    int s = sidx[e];
    int d = tidx[e];
    float w = enorm[e] * esgn[e];

    const float4* src = (const float4*)(input + (size_t)s * 32);
    float4 v = src[sub];

    float* op = out + (size_t)d * 32 + sub * 4;
    atomicAdd(op + 0, v.x * w);
    atomicAdd(op + 1, v.y * w);
    atomicAdd(op + 2, v.z * w);
    atomicAdd(op + 3, v.w * w);
}

extern "C" void kernel_launch(void* const* d_in, const int* in_sizes, int n_in,
                              void* d_out, int out_size, void* d_ws, size_t ws_size,
                              hipStream_t stream) {
    const float* input = (const float*)d_in[0];
    const int*   eidx  = (const int*)d_in[1];   // int64 in reference -> int32 here
    const float* enorm = (const float*)d_in[2];
    const float* esgn  = (const float*)d_in[3];
    float*       out   = (float*)d_out;

    int n_edges = in_sizes[1] / 2;             // eidx is (2, n_edges)
    const int* sidx = eidx;                    // eidx[0,:]
    const int* tidx = eidx + n_edges;          // eidx[1,:]

    // d_out is poisoned with 0xAA before every timed replay — zero it.
    hipMemsetAsync(d_out, 0, (size_t)out_size * sizeof(float), stream);

    size_t threads_total = (size_t)n_edges * 8;
    int block = 256;
    int grid = (int)((threads_total + block - 1) / block);
    graphconv_scatter<<<grid, block, 0, stream>>>(input, sidx, tidx, enorm, esgn,
                                                  out, n_edges);
}

// Round 4
// 799.706 us; speedup vs baseline: 1.7154x; 1.7154x over previous
//
#include <hip/hip_runtime.h>

// GraphConv: out[t] += input[s] * (esgn*enorm), 3.2M edges, 100K nodes, D=32 fp32.
// Round 4: counting-sort -> CSR-by-target per launch; accumulate with zero fp32
// atomics. R3 showed fp32 atomics write through 16B/op to HBM (1.6 GB writes).

#define NB 256

__global__ __launch_bounds__(NB) void hist_kernel(
    const int* __restrict__ tidx, int* __restrict__ counts, int n_edges)
{
    int e = blockIdx.x * NB + threadIdx.x;
    if (e < n_edges) atomicAdd(&counts[tidx[e]], 1);
}

__global__ __launch_bounds__(1024) void scan_kernel(
    const int* __restrict__ counts, int* __restrict__ offsets,
    int* __restrict__ cursors, int n_nodes)
{
    __shared__ int part[1024];
    int t = threadIdx.x;
    int chunk = (n_nodes + 1023) / 1024;
    int beg = t * chunk;
    int end = min(beg + chunk, n_nodes);
    int sum = 0;
    for (int i = beg; i < end; ++i) sum += counts[i];
    part[t] = sum;
    __syncthreads();
    // Hillis-Steele inclusive scan over 1024 partials
    for (int off = 1; off < 1024; off <<= 1) {
        int v = (t >= off) ? part[t - off] : 0;
        __syncthreads();
        part[t] += v;
        __syncthreads();
    }
    int run = (t == 0) ? 0 : part[t - 1];   // exclusive base for this chunk
    for (int i = beg; i < end; ++i) {
        offsets[i] = run;
        cursors[i] = run;
        run += counts[i];
    }
    if (t == 1023) offsets[n_nodes] = part[1023];  // total
}

__global__ __launch_bounds__(NB) void scatter_kernel(
    const int* __restrict__ sidx, const int* __restrict__ tidx,
    const float* __restrict__ enorm, const float* __restrict__ esgn,
    int* __restrict__ cursors, int* __restrict__ ssrc, float* __restrict__ sw,
    int n_edges)
{
    int e = blockIdx.x * NB + threadIdx.x;
    if (e >= n_edges) return;
    int tno = tidx[e];
    int pos = atomicAdd(&cursors[tno], 1);
    ssrc[pos] = sidx[e];
    sw[pos] = enorm[e] * esgn[e];
}

// 32 threads per node (one feature each); 8 nodes per 256-thread block.
__global__ __launch_bounds__(NB) void accum_kernel(
    const float* __restrict__ input, const int* __restrict__ offsets,
    const int* __restrict__ ssrc, const float* __restrict__ sw,
    float* __restrict__ out, int n_nodes)
{
    int f = threadIdx.x & 31;
    int n = blockIdx.x * 8 + (threadIdx.x >> 5);
    if (n >= n_nodes) return;
    int beg = offsets[n];
    int end = offsets[n + 1];
    float acc = 0.f;
    for (int i = beg; i < end; ++i) {
        int s = ssrc[i];          // same addr for 32 lanes -> one transaction
        float w = sw[i];
        acc = fmaf(w, input[(size_t)s * 32 + f], acc);  // coalesced 128B row
    }
    out[(size_t)n * 32 + f] = acc;
}

// Fallback (R3): direct atomic scatter, used only if ws_size is too small.
__global__ __launch_bounds__(NB) void graphconv_scatter(
    const float* __restrict__ input, const int* __restrict__ sidx,
    const int* __restrict__ tidx, const float* __restrict__ enorm,
    const float* __restrict__ esgn, float* __restrict__ out, int n_edges)
{
    int t = blockIdx.x * NB + threadIdx.x;
    int e = t >> 3;
    int sub = t & 7;
    if (e >= n_edges) return;
    int s = sidx[e];
    int d = tidx[e];
    float w = enorm[e] * esgn[e];
    const float4* src = (const float4*)(input + (size_t)s * 32);
    float4 v = src[sub];
    float* op = out + (size_t)d * 32 + sub * 4;
    atomicAdd(op + 0, v.x * w);
    atomicAdd(op + 1, v.y * w);
    atomicAdd(op + 2, v.z * w);
    atomicAdd(op + 3, v.w * w);
}

extern "C" void kernel_launch(void* const* d_in, const int* in_sizes, int n_in,
                              void* d_out, int out_size, void* d_ws, size_t ws_size,
                              hipStream_t stream) {
    const float* input = (const float*)d_in[0];
    const int*   eidx  = (const int*)d_in[1];   // int64 in reference -> int32 here
    const float* enorm = (const float*)d_in[2];
    const float* esgn  = (const float*)d_in[3];
    float*       out   = (float*)d_out;

    int n_edges = in_sizes[1] / 2;             // eidx is (2, n_edges)
    int n_nodes = in_sizes[0] / 32;            // input is (n_nodes, 32)
    const int* sidx = eidx;
    const int* tidx = eidx + n_edges;

    // Workspace layout (all 4-byte elems):
    //   counts[n_nodes] | offsets[n_nodes+1] | cursors[n_nodes]
    //   | ssrc[n_edges] | sw[n_edges]
    size_t need = ((size_t)3 * n_nodes + 1 + (size_t)2 * n_edges) * 4;

    if (ws_size >= need) {
        int*   counts  = (int*)d_ws;
        int*   offsets = counts + n_nodes;
        int*   cursors = offsets + (n_nodes + 1);
        int*   ssrc    = cursors + n_nodes;
        float* sw      = (float*)(ssrc + n_edges);

        hipMemsetAsync(counts, 0, (size_t)n_nodes * sizeof(int), stream);

        int eg = (n_edges + NB - 1) / NB;
        hist_kernel<<<eg, NB, 0, stream>>>(tidx, counts, n_edges);
        scan_kernel<<<1, 1024, 0, stream>>>(counts, offsets, cursors, n_nodes);
        scatter_kernel<<<eg, NB, 0, stream>>>(sidx, tidx, enorm, esgn,
                                              cursors, ssrc, sw, n_edges);
        int ng = (n_nodes + 7) / 8;
        accum_kernel<<<ng, NB, 0, stream>>>(input, offsets, ssrc, sw, out, n_nodes);
    } else {
        // Fallback: atomic scatter (R3 path)
        hipMemsetAsync(d_out, 0, (size_t)out_size * sizeof(float), stream);
        size_t threads_total = (size_t)n_edges * 8;
        int grid = (int)((threads_total + NB - 1) / NB);
        graphconv_scatter<<<grid, NB, 0, stream>>>(input, sidx, tidx, enorm, esgn,
                                                   out, n_edges);
    }
}

// Round 5
// 459.959 us; speedup vs baseline: 2.9825x; 1.7386x over previous
//
#include <hip/hip_runtime.h>

// GraphConv: out[t] += input[s] * (esgn*enorm), 3.2M edges, 100K nodes, D=32 fp32.
// Round 5: CSR build with packed int2 payload (halve scattered write lines),
// fully parallel 3-phase scan, accum with 8 lanes/node + float4.

#define NB 256

__global__ __launch_bounds__(NB) void hist_kernel(
    const int* __restrict__ tidx, int* __restrict__ counts, int n_edges)
{
    int e = blockIdx.x * NB + threadIdx.x;
    if (e < n_edges) atomicAdd(&counts[tidx[e]], 1);
}

// Phase 1: per-block sums of counts.
__global__ __launch_bounds__(NB) void scan_bsum(
    const int* __restrict__ counts, int* __restrict__ bsum, int n_nodes)
{
    __shared__ int red[NB];
    int gid = blockIdx.x * NB + threadIdx.x;
    red[threadIdx.x] = (gid < n_nodes) ? counts[gid] : 0;
    __syncthreads();
    for (int off = NB / 2; off > 0; off >>= 1) {
        if (threadIdx.x < off) red[threadIdx.x] += red[threadIdx.x + off];
        __syncthreads();
    }
    if (threadIdx.x == 0) bsum[blockIdx.x] = red[0];
}

// Phase 2: exclusive scan of block sums (nblk <= 1024), in place.
__global__ __launch_bounds__(1024) void scan_bbase(int* __restrict__ bsum, int nblk)
{
    __shared__ int part[1024];
    int t = threadIdx.x;
    part[t] = (t < nblk) ? bsum[t] : 0;
    __syncthreads();
    for (int off = 1; off < 1024; off <<= 1) {
        int v = (t >= off) ? part[t - off] : 0;
        __syncthreads();
        part[t] += v;
        __syncthreads();
    }
    if (t < nblk) bsum[t] = (t == 0) ? 0 : part[t - 1];
}

// Phase 3: per-block exclusive scan + block base -> offsets & cursors.
__global__ __launch_bounds__(NB) void scan_write(
    const int* __restrict__ counts, const int* __restrict__ bsum,
    int* __restrict__ offsets, int* __restrict__ cursors, int n_nodes)
{
    __shared__ int part[NB];
    int t = threadIdx.x;
    int gid = blockIdx.x * NB + t;
    int c = (gid < n_nodes) ? counts[gid] : 0;
    part[t] = c;
    __syncthreads();
    for (int off = 1; off < NB; off <<= 1) {
        int v = (t >= off) ? part[t - off] : 0;
        __syncthreads();
        part[t] += v;
        __syncthreads();
    }
    int excl = part[t] - c + bsum[blockIdx.x];
    if (gid < n_nodes) {
        offsets[gid] = excl;
        cursors[gid] = excl;
        if (gid == n_nodes - 1) offsets[n_nodes] = excl + c;
    }
}

// Scatter edges into target-sorted order; payload packed as (src, w) in 8 B.
__global__ __launch_bounds__(NB) void scatter_kernel(
    const int* __restrict__ sidx, const int* __restrict__ tidx,
    const float* __restrict__ enorm, const float* __restrict__ esgn,
    int* __restrict__ cursors, int2* __restrict__ sv, int n_edges)
{
    int e = blockIdx.x * NB + threadIdx.x;
    if (e >= n_edges) return;
    int tno = tidx[e];
    int pos = atomicAdd(&cursors[tno], 1);
    sv[pos] = make_int2(sidx[e], __float_as_int(enorm[e] * esgn[e]));
}

// 8 lanes per node, float4 per lane; 32 nodes per 256-thread block.
__global__ __launch_bounds__(NB) void accum_kernel(
    const float* __restrict__ input, const int* __restrict__ offsets,
    const int2* __restrict__ sv, float* __restrict__ out, int n_nodes)
{
    int l = threadIdx.x & 7;                    // float4 index within row
    int n = blockIdx.x * 32 + (threadIdx.x >> 3);
    if (n >= n_nodes) return;
    int beg = offsets[n];
    int end = offsets[n + 1];
    float4 acc = make_float4(0.f, 0.f, 0.f, 0.f);
    for (int i = beg; i < end; ++i) {
        int2 e = sv[i];                          // broadcast within group
        float w = __int_as_float(e.y);
        float4 v = ((const float4*)(input + (size_t)e.x * 32))[l];
        acc.x = fmaf(w, v.x, acc.x);
        acc.y = fmaf(w, v.y, acc.y);
        acc.z = fmaf(w, v.z, acc.z);
        acc.w = fmaf(w, v.w, acc.w);
    }
    ((float4*)(out + (size_t)n * 32))[l] = acc;
}

// Fallback (R3): direct atomic scatter, used only if ws_size is too small.
__global__ __launch_bounds__(NB) void graphconv_scatter(
    const float* __restrict__ input, const int* __restrict__ sidx,
    const int* __restrict__ tidx, const float* __restrict__ enorm,
    const float* __restrict__ esgn, float* __restrict__ out, int n_edges)
{
    int t = blockIdx.x * NB + threadIdx.x;
    int e = t >> 3;
    int sub = t & 7;
    if (e >= n_edges) return;
    int s = sidx[e];
    int d = tidx[e];
    float w = enorm[e] * esgn[e];
    const float4* src = (const float4*)(input + (size_t)s * 32);
    float4 v = src[sub];
    float* op = out + (size_t)d * 32 + sub * 4;
    atomicAdd(op + 0, v.x * w);
    atomicAdd(op + 1, v.y * w);
    atomicAdd(op + 2, v.z * w);
    atomicAdd(op + 3, v.w * w);
}

extern "C" void kernel_launch(void* const* d_in, const int* in_sizes, int n_in,
                              void* d_out, int out_size, void* d_ws, size_t ws_size,
                              hipStream_t stream) {
    const float* input = (const float*)d_in[0];
    const int*   eidx  = (const int*)d_in[1];   // int64 in reference -> int32 here
    const float* enorm = (const float*)d_in[2];
    const float* esgn  = (const float*)d_in[3];
    float*       out   = (float*)d_out;

    int n_edges = in_sizes[1] / 2;             // eidx is (2, n_edges)
    int n_nodes = in_sizes[0] / 32;            // input is (n_nodes, 32)
    const int* sidx = eidx;
    const int* tidx = eidx + n_edges;

    int nblk = (n_nodes + NB - 1) / NB;        // 391 for 100K; must be <= 1024

    // Workspace layout: sv[int2 x n_edges] FIRST (8B-aligned), then int arrays:
    //   counts[n_nodes] | offsets[n_nodes+1] | cursors[n_nodes] | bsum[nblk]
    size_t need = (size_t)n_edges * 8 +
                  ((size_t)3 * n_nodes + 1 + (size_t)nblk) * 4;

    if (ws_size >= need && nblk <= 1024) {
        int2* sv      = (int2*)d_ws;
        int*  counts  = (int*)(sv + n_edges);
        int*  offsets = counts + n_nodes;
        int*  cursors = offsets + (n_nodes + 1);
        int*  bsum    = cursors + n_nodes;

        hipMemsetAsync(counts, 0, (size_t)n_nodes * sizeof(int), stream);

        int eg = (n_edges + NB - 1) / NB;
        hist_kernel <<<eg,   NB,   0, stream>>>(tidx, counts, n_edges);
        scan_bsum   <<<nblk, NB,   0, stream>>>(counts, bsum, n_nodes);
        scan_bbase  <<<1,    1024, 0, stream>>>(bsum, nblk);
        scan_write  <<<nblk, NB,   0, stream>>>(counts, bsum, offsets, cursors,
                                                n_nodes);
        scatter_kernel<<<eg, NB,   0, stream>>>(sidx, tidx, enorm, esgn,
                                                cursors, sv, n_edges);
        int ng = (n_nodes + 31) / 32;
        accum_kernel<<<ng,   NB,   0, stream>>>(input, offsets, sv, out, n_nodes);
    } else {
        hipMemsetAsync(d_out, 0, (size_t)out_size * sizeof(float), stream);
        size_t threads_total = (size_t)n_edges * 8;
        int grid = (int)((threads_total + NB - 1) / NB);
        graphconv_scatter<<<grid, NB, 0, stream>>>(input, sidx, tidx, enorm, esgn,
                                                   out, n_edges);
    }
}